// Round 1
// baseline (231.247 us; speedup 1.0000x reference)
//
#include <hip/hip_runtime.h>

#define D 128

__global__ __launch_bounds__(256) void transr_kernel(
    const float* __restrict__ head,
    const float* __restrict__ tail,
    const float* __restrict__ edge,
    const float* __restrict__ proj,
    const int* __restrict__ idx,
    float* __restrict__ out)
{
    const int b   = blockIdx.x;
    const int tid = threadIdx.x;

    __shared__ float u_lds[D];      // u = h/||h|| - t/||t||
    __shared__ float r_lds[D];      // edge embedding
    __shared__ float wsum[4][2];    // per-wave norm partials
    __shared__ float red[8];        // final diff^2 partials

    // ---- Phase 0: load h,t,r; compute u = normalize(h) - normalize(t) ----
    float hv = 0.f, tv = 0.f;
    if (tid < D) {
        hv = head[(size_t)b * D + tid];
        tv = tail[(size_t)b * D + tid];
        r_lds[tid] = edge[(size_t)b * D + tid];
    }
    float hs = hv * hv, ts = tv * tv;
    #pragma unroll
    for (int m = 1; m < 64; m <<= 1) {
        hs += __shfl_xor(hs, m);
        ts += __shfl_xor(ts, m);
    }
    const int wave = tid >> 6;
    if ((tid & 63) == 0) { wsum[wave][0] = hs; wsum[wave][1] = ts; }
    __syncthreads();
    if (tid < D) {
        float hn = fmaxf(sqrtf(wsum[0][0] + wsum[1][0]), 1e-12f);
        float tn = fmaxf(sqrtf(wsum[0][1] + wsum[1][1]), 1e-12f);
        u_lds[tid] = hv / hn - tv / tn;
    }
    __syncthreads();

    // ---- Phase 1: dot rows of P with u; score = -sum((P u + r)^2) ----
    // float4 index f = tid + 256*i over [0,4096): row = (tid>>5)+8i, col4 = tid&31.
    const float4 u4 = *reinterpret_cast<const float4*>(&u_lds[(tid & 31) * 4]);
    const size_t rel = (size_t)idx[b];
    const float4* __restrict__ P4 =
        reinterpret_cast<const float4*>(proj + rel * (size_t)(D * D));

    float acc[16];
    #pragma unroll
    for (int i = 0; i < 16; ++i) {
        float4 p = P4[tid + i * 256];
        float a;
        a = p.x * u4.x;
        a = fmaf(p.y, u4.y, a);
        a = fmaf(p.z, u4.z, a);
        a = fmaf(p.w, u4.w, a);
        acc[i] = a;
    }

    // reduce each partial over the 32-lane column group
    #pragma unroll
    for (int i = 0; i < 16; ++i) {
        float v = acc[i];
        v += __shfl_xor(v, 1);
        v += __shfl_xor(v, 2);
        v += __shfl_xor(v, 4);
        v += __shfl_xor(v, 8);
        v += __shfl_xor(v, 16);
        acc[i] = v;
    }

    if ((tid & 31) == 0) {
        const int r0 = tid >> 5;           // 0..7
        float local = 0.f;
        #pragma unroll
        for (int i = 0; i < 16; ++i) {
            const int r = r0 + 8 * i;      // each row covered exactly once
            const float dfr = acc[i] + r_lds[r];
            local = fmaf(dfr, dfr, local);
        }
        red[r0] = local;
    }
    __syncthreads();

    if (tid == 0) {
        float s = 0.f;
        #pragma unroll
        for (int i = 0; i < 8; ++i) s += red[i];
        out[b] = -s;
    }
}

extern "C" void kernel_launch(void* const* d_in, const int* in_sizes, int n_in,
                              void* d_out, int out_size, void* d_ws, size_t ws_size,
                              hipStream_t stream) {
    const float* head = (const float*)d_in[0];
    const float* tail = (const float*)d_in[1];
    const float* edge = (const float*)d_in[2];
    const float* proj = (const float*)d_in[3];
    const int*   idx  = (const int*)d_in[4];
    float* out = (float*)d_out;

    const int B = in_sizes[0] / D;   // 16384
    transr_kernel<<<B, 256, 0, stream>>>(head, tail, edge, proj, idx, out);
}

// Round 2
// 146.014 us; speedup vs baseline: 1.5837x; 1.5837x over previous
//
#include <hip/hip_runtime.h>

#define D 128

// ---------------- prep kernels: bucket batch elements by relation ----------------

__global__ __launch_bounds__(256) void k_zero(int* counts) {
    const int t = threadIdx.x;
    #pragma unroll
    for (int i = 0; i < 4; ++i) counts[t + 256 * i] = 0;
}

__global__ __launch_bounds__(256) void k_hist(const int* __restrict__ idx,
                                              int* __restrict__ counts, int B) {
    const int i = blockIdx.x * 256 + threadIdx.x;
    if (i < B) atomicAdd(&counts[idx[i]], 1);
}

__global__ __launch_bounds__(1024) void k_scan(const int* __restrict__ counts,
                                               int* __restrict__ offsets,
                                               int* __restrict__ cursor, int nrel) {
    __shared__ int s[1024];
    const int t = threadIdx.x;
    const int c0 = (t < nrel) ? counts[t] : 0;
    s[t] = c0;
    __syncthreads();
    #pragma unroll
    for (int d = 1; d < 1024; d <<= 1) {
        int v = (t >= d) ? s[t - d] : 0;
        __syncthreads();
        s[t] += v;
        __syncthreads();
    }
    if (t < nrel) {
        const int excl = s[t] - c0;     // exclusive prefix
        offsets[t] = excl;
        cursor[t]  = excl;
        if (t == nrel - 1) offsets[nrel] = s[t];
    }
}

__global__ __launch_bounds__(256) void k_scat(const int* __restrict__ idx,
                                              int* __restrict__ cursor,
                                              int* __restrict__ bucket, int B) {
    const int i = blockIdx.x * 256 + threadIdx.x;
    if (i < B) {
        const int pos = atomicAdd(&cursor[idx[i]], 1);
        bucket[pos] = i;
    }
}

// ---------------- main kernel: one block per relation ----------------
// LDS: P (128x128 f32, XOR-swizzled quads) + U[8][128] + R[8][128] + E[8]

#define SMEM_BYTES ((16384 + 1024 + 1024) * 4 + 8 * 4)

__global__ __launch_bounds__(256) void transr_main(
    const float* __restrict__ head,
    const float* __restrict__ tail,
    const float* __restrict__ edge,
    const float* __restrict__ proj,
    const int* __restrict__ bucket,
    const int* __restrict__ offsets,
    float* __restrict__ out)
{
    const int rel = blockIdx.x;
    const int tid = threadIdx.x;
    const int start = offsets[rel];
    const int n = offsets[rel + 1] - start;
    if (n == 0) return;

    extern __shared__ float sm[];
    float* Pl = sm;                      // 16384 floats, swizzled
    float* Ul = sm + 16384;              // 8 x 128
    float* Rl = sm + 16384 + 1024;       // 8 x 128
    int*   El = (int*)(sm + 16384 + 2048); // 8 element ids (-1 = invalid)

    // ---- stage P: global float4 (coalesced) -> regs -> swizzled LDS ----
    const float4* __restrict__ Pg =
        reinterpret_cast<const float4*>(proj + (size_t)rel * (D * D));
    float4 stg[16];
    #pragma unroll
    for (int i = 0; i < 16; ++i) stg[i] = Pg[tid + 256 * i];
    #pragma unroll
    for (int i = 0; i < 16; ++i) {
        const int f = tid + 256 * i;
        const int row = f >> 5;          // 0..127
        const int q = f & 31;            // quad within row
        const int phys = row * D + 4 * (q ^ (row & 31));
        *reinterpret_cast<float4*>(Pl + phys) = stg[i];
    }

    const int g = tid >> 5;   // element group 0..7 (Phase A)
    const int l = tid & 31;   // lane within group
    const int wv = tid >> 6;  // wave 0..3 (Phase B)
    const int wl = tid & 63;  // lane within wave

    const int nchunk = (n + 7) >> 3;
    for (int ch = 0; ch < nchunk; ++ch) {
        __syncthreads();   // prev Phase B done reading U/R/E (no-op on ch=0)

        // ---- Phase A: per-32-lane-group normalize, u = h/|h| - t/|t| ----
        const int e = ch * 8 + g;
        float4 u4 = make_float4(0.f, 0.f, 0.f, 0.f);
        float4 r4 = make_float4(0.f, 0.f, 0.f, 0.f);
        int b = -1;
        if (e < n) {
            b = bucket[start + e];
            const float4 h4 = *reinterpret_cast<const float4*>(head + (size_t)b * D + 4 * l);
            const float4 t4 = *reinterpret_cast<const float4*>(tail + (size_t)b * D + 4 * l);
            r4 = *reinterpret_cast<const float4*>(edge + (size_t)b * D + 4 * l);
            float hs = h4.x * h4.x + h4.y * h4.y + h4.z * h4.z + h4.w * h4.w;
            float ts = t4.x * t4.x + t4.y * t4.y + t4.z * t4.z + t4.w * t4.w;
            #pragma unroll
            for (int m = 1; m < 32; m <<= 1) {
                hs += __shfl_xor(hs, m);
                ts += __shfl_xor(ts, m);
            }
            const float hn = fmaxf(sqrtf(hs), 1e-12f);
            const float tn = fmaxf(sqrtf(ts), 1e-12f);
            u4.x = h4.x / hn - t4.x / tn;
            u4.y = h4.y / hn - t4.y / tn;
            u4.z = h4.z / hn - t4.z / tn;
            u4.w = h4.w / hn - t4.w / tn;
        }
        *reinterpret_cast<float4*>(Ul + g * D + 4 * l) = u4;
        *reinterpret_cast<float4*>(Rl + g * D + 4 * l) = r4;
        if (l == 0) El[g] = b;
        __syncthreads();

        // ---- Phase B: wave wv handles elements e0,e1; lane wl rows wl, wl+64 ----
        const int e0 = 2 * wv, e1 = 2 * wv + 1;
        float acc00 = 0.f, acc01 = 0.f, acc10 = 0.f, acc11 = 0.f;
        const float* P0 = Pl + wl * D;
        const float* P1 = Pl + (wl + 64) * D;
        const float* U0 = Ul + e0 * D;
        const float* U1 = Ul + e1 * D;
        const int sx = wl & 31;
        #pragma unroll
        for (int q = 0; q < 32; ++q) {
            const float4 pA = *reinterpret_cast<const float4*>(P0 + 4 * (q ^ sx));
            const float4 pB = *reinterpret_cast<const float4*>(P1 + 4 * (q ^ sx));
            const float4 uA = *reinterpret_cast<const float4*>(U0 + 4 * q);
            const float4 uB = *reinterpret_cast<const float4*>(U1 + 4 * q);
            acc00 = fmaf(pA.x, uA.x, acc00); acc00 = fmaf(pA.y, uA.y, acc00);
            acc00 = fmaf(pA.z, uA.z, acc00); acc00 = fmaf(pA.w, uA.w, acc00);
            acc01 = fmaf(pA.x, uB.x, acc01); acc01 = fmaf(pA.y, uB.y, acc01);
            acc01 = fmaf(pA.z, uB.z, acc01); acc01 = fmaf(pA.w, uB.w, acc01);
            acc10 = fmaf(pB.x, uA.x, acc10); acc10 = fmaf(pB.y, uA.y, acc10);
            acc10 = fmaf(pB.z, uA.z, acc10); acc10 = fmaf(pB.w, uA.w, acc10);
            acc11 = fmaf(pB.x, uB.x, acc11); acc11 = fmaf(pB.y, uB.y, acc11);
            acc11 = fmaf(pB.z, uB.z, acc11); acc11 = fmaf(pB.w, uB.w, acc11);
        }
        // diff = P.u + r per row; accumulate squared over 128 rows (64 lanes x 2)
        float d;
        float s0 = 0.f, s1 = 0.f;
        d = acc00 + Rl[e0 * D + wl];      s0 = fmaf(d, d, s0);
        d = acc10 + Rl[e0 * D + wl + 64]; s0 = fmaf(d, d, s0);
        d = acc01 + Rl[e1 * D + wl];      s1 = fmaf(d, d, s1);
        d = acc11 + Rl[e1 * D + wl + 64]; s1 = fmaf(d, d, s1);
        #pragma unroll
        for (int m = 1; m < 64; m <<= 1) {
            s0 += __shfl_xor(s0, m);
            s1 += __shfl_xor(s1, m);
        }
        if (wl == 0) {
            const int bA = El[e0];
            const int bB = El[e1];
            if (bA >= 0) out[bA] = -s0;
            if (bB >= 0) out[bB] = -s1;
        }
    }
}

// ---------------- launch ----------------

extern "C" void kernel_launch(void* const* d_in, const int* in_sizes, int n_in,
                              void* d_out, int out_size, void* d_ws, size_t ws_size,
                              hipStream_t stream) {
    const float* head = (const float*)d_in[0];
    const float* tail = (const float*)d_in[1];
    const float* edge = (const float*)d_in[2];
    const float* proj = (const float*)d_in[3];
    const int*   idx  = (const int*)d_in[4];
    float* out = (float*)d_out;

    const int B    = in_sizes[0] / D;          // 16384
    const int nrel = in_sizes[3] / (D * D);    // 1000 (assumed <= 1024)

    int* wsi     = (int*)d_ws;
    int* counts  = wsi;           // 1024
    int* offsets = wsi + 1024;    // nrel+1 (<= 1056)
    int* cursor  = wsi + 2080;    // 1024
    int* bucket  = wsi + 3104;    // B

    const int gridB = (B + 255) / 256;

    k_zero<<<1, 256, 0, stream>>>(counts);
    k_hist<<<gridB, 256, 0, stream>>>(idx, counts, B);
    k_scan<<<1, 1024, 0, stream>>>(counts, offsets, cursor, nrel);
    k_scat<<<gridB, 256, 0, stream>>>(idx, cursor, bucket, B);

    hipFuncSetAttribute(reinterpret_cast<const void*>(transr_main),
                        hipFuncAttributeMaxDynamicSharedMemorySize, SMEM_BYTES);
    transr_main<<<nrel, 256, SMEM_BYTES, stream>>>(head, tail, edge, proj,
                                                   bucket, offsets, out);
}